// Round 3
// baseline (9539.943 us; speedup 1.0000x reference)
//
#include <hip/hip_runtime.h>
#include <math.h>

#define B_   64
#define T_   512
#define EMB_ 128
#define E_   256
#define H_   384
#define G4_  1536   // 4*H
#define K_   13

typedef __fp16 h2v __attribute__((ext_vector_type(2)));
typedef float  f2v __attribute__((ext_vector_type(2)));

#if __has_builtin(__builtin_amdgcn_fdot2)
#define DOT2(w,x,c) __builtin_amdgcn_fdot2((w),(x),(c),false)
#else
#define DOT2(w,x,c) ((c) + (float)(w)[0]*(float)(x)[0] + (float)(w)[1]*(float)(x)[1])
#endif

__device__ __forceinline__ float sigm(float x){ return 1.f/(1.f+__expf(-x)); }
__device__ __forceinline__ h2v h2zero(){ return __builtin_bit_cast(h2v, 0u); }

// ---------- K0: pack fp32 W [1536][K] (row-major) -> h2v [K/2][1536] (transposed, fp16-paired)
__global__ __launch_bounds__(256) void k_pack(const float* __restrict__ src, h2v* __restrict__ dst, int K){
  int i = blockIdx.x*256 + threadIdx.x;
  if (i >= (K/2)*G4_) return;
  int k2 = i / G4_, row = i % G4_;
  float a = src[row*K + 2*k2];
  float b = src[row*K + 2*k2 + 1];
  dst[i] = __builtin_amdgcn_cvt_pkrtz(a, b);
}

// ---------- K1: fused LSTM: input GEMM + recurrence + emission partials.
// 64 blocks = 32 batch-pairs x 2 dirs; fwd on XCDs 0-3, bwd on 4-7.
__global__ __launch_bounds__(384) void k_lstm(
    const h2v* __restrict__ wTih_f, const h2v* __restrict__ wTih_b,   // [128][1536]
    const h2v* __restrict__ wThh_f, const h2v* __restrict__ wThh_b,   // [192][1536]
    const float* __restrict__ b_f,  const float* __restrict__ b_b,
    const int* __restrict__ char_id, const int* __restrict__ bichar_id,
    const float* __restrict__ char_table, const float* __restrict__ bichar_table,
    const float* __restrict__ w_em,
    float* __restrict__ em_pf, float* __restrict__ em_pb)
{
  __shared__ float gl[2][G4_];          // gate pre-activations, 2 batches
  __shared__ h2v   hs2[2][H_/2];        // hidden state fp16-paired
  __shared__ h2v   xs2[2][2][E_/2];     // [buf][batch][k2] input embeddings fp16-paired
  __shared__ float wem[K_][H_];         // emission weight slice for this dir

  const int bid  = blockIdx.x;
  const int dir  = (bid & 4) ? 1 : 0;
  const int pair = ((bid >> 3) << 2) | (bid & 3);   // 0..31, each (pair,dir) once
  const int b0   = pair*2;

  const h2v* __restrict__ wTih = dir ? wTih_b : wTih_f;
  const h2v* __restrict__ wThh = dir ? wThh_b : wThh_f;
  const float* bias = dir ? b_b : b_f;
  float* em_p = dir ? em_pb : em_pf;

  const int tid  = threadIdx.x;          // 0..383
  const int lane = tid & 63, wv = tid >> 6;
  const int gate = tid / 96, u = tid % 96;
  const int rowbase = gate*H_ + 4*u;     // 4 consecutive rows of one gate

  for (int i = tid; i < K_*H_; i += 384)
    wem[i/H_][i%H_] = w_em[(i/H_)*(2*H_) + dir*H_ + (i%H_)];

  hs2[tid/(H_/2)][tid%(H_/2)] = h2zero();   // 384 entries exactly

  const int pf_bi = tid >> 7, pf_k2 = tid & 127;
  if (tid < 256) {
    int t0 = dir ? (T_-1) : 0;
    int kk = pf_k2*2, b = b0 + pf_bi;
    f2v v;
    if (kk < EMB_) { int c = char_id  [b*T_ + t0]; v = *(const f2v*)(char_table  + (size_t)c*EMB_ + kk); }
    else           { int c = bichar_id[b*T_ + t0]; v = *(const f2v*)(bichar_table+ (size_t)c*EMB_ + (kk-EMB_)); }
    xs2[0][pf_bi][pf_k2] = __builtin_amdgcn_cvt_pkrtz(v[0], v[1]);
  }

  const float4 bb = *(const float4*)(bias + rowbase);
  float c0 = 0.f, c1 = 0.f;
  __syncthreads();

  for (int s = 0; s < T_; s++) {
    const int t = dir ? (T_-1-s) : s;
    const int cur = s & 1, nxt = cur ^ 1;

    // prefetch next step's embeddings into regs (latency hidden under dot loops)
    f2v pf;
    const bool doPf = (s+1 < T_) && (tid < 256);
    if (doPf) {
      int tn = dir ? (T_-2-s) : (s+1);
      int kk = pf_k2*2, b = b0 + pf_bi;
      if (kk < EMB_) { int c = char_id  [b*T_ + tn]; pf = *(const f2v*)(char_table  + (size_t)c*EMB_ + kk); }
      else           { int c = bichar_id[b*T_ + tn]; pf = *(const f2v*)(bichar_table+ (size_t)c*EMB_ + (kk-EMB_)); }
    }

    // ---- phase 1: g = b + W_ih x_t + W_hh h_{t-1}  (4 rows x 2 batches per thread)
    float4 a0 = bb, a1 = bb;
    {
      const h2v* wp = wTih + rowbase;
      #pragma unroll 8
      for (int k2 = 0; k2 < E_/2; k2++) {
        h2v x0 = xs2[cur][0][k2], x1 = xs2[cur][1][k2];
        float4 wq = *(const float4*)(wp + (size_t)k2*G4_);
        h2v w0 = __builtin_bit_cast(h2v, wq.x);
        h2v w1 = __builtin_bit_cast(h2v, wq.y);
        h2v w2 = __builtin_bit_cast(h2v, wq.z);
        h2v w3 = __builtin_bit_cast(h2v, wq.w);
        a0.x = DOT2(w0,x0,a0.x); a0.y = DOT2(w1,x0,a0.y);
        a0.z = DOT2(w2,x0,a0.z); a0.w = DOT2(w3,x0,a0.w);
        a1.x = DOT2(w0,x1,a1.x); a1.y = DOT2(w1,x1,a1.y);
        a1.z = DOT2(w2,x1,a1.z); a1.w = DOT2(w3,x1,a1.w);
      }
    }
    {
      const h2v* wp = wThh + rowbase;
      #pragma unroll 8
      for (int k2 = 0; k2 < H_/2; k2++) {
        h2v h0 = hs2[0][k2], h1 = hs2[1][k2];
        float4 wq = *(const float4*)(wp + (size_t)k2*G4_);
        h2v w0 = __builtin_bit_cast(h2v, wq.x);
        h2v w1 = __builtin_bit_cast(h2v, wq.y);
        h2v w2 = __builtin_bit_cast(h2v, wq.z);
        h2v w3 = __builtin_bit_cast(h2v, wq.w);
        a0.x = DOT2(w0,h0,a0.x); a0.y = DOT2(w1,h0,a0.y);
        a0.z = DOT2(w2,h0,a0.z); a0.w = DOT2(w3,h0,a0.w);
        a1.x = DOT2(w0,h1,a1.x); a1.y = DOT2(w1,h1,a1.y);
        a1.z = DOT2(w2,h1,a1.z); a1.w = DOT2(w3,h1,a1.w);
      }
    }
    *(float4*)&gl[0][rowbase] = a0;
    *(float4*)&gl[1][rowbase] = a1;
    if (doPf) xs2[nxt][pf_bi][pf_k2] = __builtin_amdgcn_cvt_pkrtz(pf[0], pf[1]);
    __syncthreads();

    // ---- phase 2: elementwise gates; thread owns h index j = tid for both batches
    {
      int j = tid;
      float gi0 = gl[0][j], gf0 = gl[0][H_+j], gg0 = gl[0][2*H_+j], go0 = gl[0][3*H_+j];
      float gi1 = gl[1][j], gf1 = gl[1][H_+j], gg1 = gl[1][2*H_+j], go1 = gl[1][3*H_+j];
      c0 = sigm(gf0)*c0 + sigm(gi0)*tanhf(gg0);
      float h0 = sigm(go0)*tanhf(c0);
      c1 = sigm(gf1)*c1 + sigm(gi1)*tanhf(gg1);
      float h1 = sigm(go1)*tanhf(c1);
      float h0n = __shfl_down(h0, 1);
      float h1n = __shfl_down(h1, 1);
      if (!(tid & 1)) {
        hs2[0][tid>>1] = __builtin_amdgcn_cvt_pkrtz(h0, h0n);
        hs2[1][tid>>1] = __builtin_amdgcn_cvt_pkrtz(h1, h1n);
      }
    }
    __syncthreads();

    // ---- phase 3: emission partial logits: 26 jobs (13 k x 2 batches) over 6 waves
    for (int job = wv; job < 2*K_; job += 6) {
      int k = job >> 1, bi = job & 1;
      float acc = 0.f;
      #pragma unroll
      for (int m = 0; m < H_/64; m++) {
        int jj = m*64 + lane;
        h2v hp = hs2[bi][jj>>1];
        float hv = (jj & 1) ? (float)hp[1] : (float)hp[0];
        acc += hv * wem[k][jj];
      }
      #pragma unroll
      for (int off = 32; off; off >>= 1) acc += __shfl_xor(acc, off, 64);
      if (lane == 0) em_p[((size_t)(b0+bi)*T_ + t)*K_ + k] = acc;
    }
    __syncthreads();
  }
}

// ---------- K2: combine emission partials + bias, log_softmax over K
__global__ __launch_bounds__(256) void k_em(
    const float* __restrict__ em_pf, const float* __restrict__ em_pb,
    const float* __restrict__ b_em, float* __restrict__ em)
{
  int r = blockIdx.x*256 + threadIdx.x;      // 0..32767
  float e[K_]; float mx = -1e30f;
  #pragma unroll
  for (int k = 0; k < K_; k++) {
    e[k] = em_pf[(size_t)r*K_+k] + em_pb[(size_t)r*K_+k] + b_em[k];
    mx = fmaxf(mx, e[k]);
  }
  float S = 0.f;
  #pragma unroll
  for (int k = 0; k < K_; k++) S += __expf(e[k]-mx);
  float L = __logf(S) + mx;
  #pragma unroll
  for (int k = 0; k < K_; k++) em[(size_t)r*K_+k] = e[k] - L;
}

// ---------- K3: CRF per-sequence gold score + forward algorithm
__global__ __launch_bounds__(64) void k_crf(
    const int* __restrict__ char_id, const int* __restrict__ label_id,
    const float* __restrict__ em,
    const float* __restrict__ start_trans, const float* __restrict__ end_trans,
    const float* __restrict__ trans, float* __restrict__ llh)
{
  int b = blockIdx.x, lane = threadIdx.x;
  const int*   cid = char_id  + b*T_;
  const int*   tag = label_id + b*T_;
  const float* emb = em + (size_t)b*T_*K_;

  float sc = 0.f; int cnt = 0;
  for (int t = lane; t < T_; t += 64) {
    int m = (cid[t] != 0);
    cnt += m;
    if (t >= 1 && m) sc += trans[tag[t-1]*K_ + tag[t]] + emb[t*K_ + tag[t]];
  }
  #pragma unroll
  for (int off = 32; off; off >>= 1) { sc += __shfl_xor(sc, off, 64); cnt += __shfl_xor(cnt, off, 64); }

  __shared__ float alpha[K_];
  __shared__ float scoreSh;
  if (lane == 0) {
    int t0 = tag[0];
    int ce = (cnt > 0) ? (cnt - 1) : 0;
    scoreSh = start_trans[t0] + emb[t0] + sc + end_trans[tag[ce]];
  }
  if (lane < K_) alpha[lane] = start_trans[lane] + emb[lane];
  float tr[K_];
  if (lane < K_) {
    #pragma unroll
    for (int i = 0; i < K_; i++) tr[i] = trans[i*K_ + lane];
  }
  __syncthreads();

  for (int t = 1; t < T_; t++) {
    bool mt = (cid[t] != 0);
    float nxt = 0.f;
    if (lane < K_) {
      float a[K_];
      #pragma unroll
      for (int i = 0; i < K_; i++) a[i] = alpha[i] + tr[i];
      float m = a[0];
      #pragma unroll
      for (int i = 1; i < K_; i++) m = fmaxf(m, a[i]);
      float s = 0.f;
      #pragma unroll
      for (int i = 0; i < K_; i++) s += __expf(a[i]-m);
      nxt = m + __logf(s) + emb[t*K_ + lane];
    }
    __syncthreads();
    if (lane < K_ && mt) alpha[lane] = nxt;
    __syncthreads();
  }

  if (lane == 0) {
    float m = alpha[0] + end_trans[0];
    #pragma unroll
    for (int k = 1; k < K_; k++) m = fmaxf(m, alpha[k]+end_trans[k]);
    float s = 0.f;
    #pragma unroll
    for (int k = 0; k < K_; k++) s += __expf(alpha[k]+end_trans[k]-m);
    llh[b] = scoreSh - (m + __logf(s));
  }
}

// ---------- K4: out = -mean(llh)
__global__ __launch_bounds__(64) void k_final(const float* __restrict__ llh, float* __restrict__ out){
  float v = llh[threadIdx.x];
  #pragma unroll
  for (int off = 32; off; off >>= 1) v += __shfl_xor(v, off, 64);
  if (threadIdx.x == 0) out[0] = -v / (float)B_;
}

extern "C" void kernel_launch(void* const* d_in, const int* in_sizes, int n_in,
                              void* d_out, int out_size, void* d_ws, size_t ws_size,
                              hipStream_t stream)
{
  const int*   char_id      = (const int*)  d_in[0];
  const int*   bichar_id    = (const int*)  d_in[1];
  const int*   label_id     = (const int*)  d_in[2];
  const float* char_table   = (const float*)d_in[3];
  const float* bichar_table = (const float*)d_in[4];
  const float* w_ih_f       = (const float*)d_in[5];
  const float* w_hh_f       = (const float*)d_in[6];
  const float* b_f          = (const float*)d_in[7];
  const float* w_ih_b       = (const float*)d_in[8];
  const float* w_hh_b       = (const float*)d_in[9];
  const float* b_b          = (const float*)d_in[10];
  const float* w_em         = (const float*)d_in[11];
  const float* b_em         = (const float*)d_in[12];
  const float* start_trans  = (const float*)d_in[13];
  const float* end_trans    = (const float*)d_in[14];
  const float* trans        = (const float*)d_in[15];

  // workspace carve (bytes); total ~8.6 MB
  char* w = (char*)d_ws;
  h2v* wTih_f = (h2v*)w; w += (size_t)(E_/2)*G4_*sizeof(h2v);   // 786,432 B
  h2v* wTih_b = (h2v*)w; w += (size_t)(E_/2)*G4_*sizeof(h2v);
  h2v* wThh_f = (h2v*)w; w += (size_t)(H_/2)*G4_*sizeof(h2v);   // 1,179,648 B
  h2v* wThh_b = (h2v*)w; w += (size_t)(H_/2)*G4_*sizeof(h2v);
  float* em_pf = (float*)w; w += (size_t)B_*T_*K_*sizeof(float); // 1,703,936 B
  float* em_pb = (float*)w; w += (size_t)B_*T_*K_*sizeof(float);
  float* em    = (float*)w; w += (size_t)B_*T_*K_*sizeof(float);
  float* llh   = (float*)w; w += 256;

  k_pack<<<((E_/2)*G4_+255)/256, 256, 0, stream>>>(w_ih_f, wTih_f, E_);
  k_pack<<<((E_/2)*G4_+255)/256, 256, 0, stream>>>(w_ih_b, wTih_b, E_);
  k_pack<<<((H_/2)*G4_+255)/256, 256, 0, stream>>>(w_hh_f, wThh_f, H_);
  k_pack<<<((H_/2)*G4_+255)/256, 256, 0, stream>>>(w_hh_b, wThh_b, H_);

  k_lstm<<<64, 384, 0, stream>>>(wTih_f, wTih_b, wThh_f, wThh_b, b_f, b_b,
                                 char_id, bichar_id, char_table, bichar_table,
                                 w_em, em_pf, em_pb);

  k_em<<<B_*T_/256, 256, 0, stream>>>(em_pf, em_pb, b_em, em);
  k_crf<<<B_, 64, 0, stream>>>(char_id, label_id, em, start_trans, end_trans, trans, llh);
  k_final<<<1, 64, 0, stream>>>(llh, (float*)d_out);
}

// Round 4
// 3956.915 us; speedup vs baseline: 2.4110x; 2.4110x over previous
//
#include <hip/hip_runtime.h>
#include <math.h>

#define B_    64
#define T_    512
#define EMB_  128
#define E_    256
#define H_    384
#define G4_   1536
#define K_    13
#define NG_   12      // unit-groups per dir (32 units each)
#define NBG_  2       // batch-groups (32 batches each)
#define GRP_  12      // blocks per sync group

typedef short s8v  __attribute__((ext_vector_type(8)));
typedef short s4v  __attribute__((ext_vector_type(4)));
typedef float f4v  __attribute__((ext_vector_type(4)));

__device__ __forceinline__ float sigm(float x){ return 1.f/(1.f+__expf(-x)); }
__device__ __forceinline__ float tanh_f(float x){ return 2.f/(1.f+__expf(-2.f*x)) - 1.f; }
__device__ __forceinline__ short f2bf(float x){
  unsigned u = __builtin_bit_cast(unsigned, x);
  return (short)((u + 0x7FFFu + ((u>>16)&1u)) >> 16);
}
__device__ __forceinline__ float bf2f(short s){
  return __builtin_bit_cast(float, ((unsigned)(unsigned short)s) << 16);
}

// ---------- K0: pack weights into per-lane MFMA A-fragments (bf16)
// Apack[dir][g][w][kt][lane] : 16B each. Row R = (w>>1)*384 + g*32 + (w&1)*16 + (lane&15)
// k = kt*32 + (lane>>4)*8 + e ;  k<256 -> w_ih[R][k] else w_hh[R][k-256]
__global__ __launch_bounds__(256) void k_packA(
    const float* __restrict__ wih_f, const float* __restrict__ whh_f,
    const float* __restrict__ wih_b, const float* __restrict__ whh_b,
    s8v* __restrict__ Apack)
{
  int idx = blockIdx.x*256 + threadIdx.x;            // 0..245759
  if (idx >= 2*NG_*8*20*64) return;
  int l   = idx & 63;
  int kt  = (idx>>6) % 20;
  int w   = ((idx>>6)/20) % 8;
  int g   = ((idx>>6)/160) % NG_;
  int dir = (idx>>6)/(160*NG_);
  const float* wih = dir ? wih_b : wih_f;
  const float* whh = dir ? whh_b : whh_f;
  int R = (w>>1)*384 + g*32 + (w&1)*16 + (l&15);
  int kbase = kt*32 + (l>>4)*8;
  const float* src = (kbase < E_) ? (wih + (size_t)R*E_ + kbase)
                                  : (whh + (size_t)R*H_ + (kbase - E_));
  s8v out;
  #pragma unroll
  for (int e = 0; e < 8; e++) out[e] = f2bf(src[e]);
  Apack[idx] = out;
}

// ---------- K1: gather embeddings -> X_all[t][b][256] bf16
__global__ __launch_bounds__(256) void k_embX(
    const int* __restrict__ char_id, const int* __restrict__ bichar_id,
    const float* __restrict__ char_table, const float* __restrict__ bichar_table,
    short* __restrict__ X_all)
{
  int rid  = blockIdx.x*4 + (threadIdx.x>>6);        // 0..32767 = t*64+b
  int lane = threadIdx.x & 63;
  int t = rid >> 6, b = rid & 63;
  float4 v;
  if (lane < 32) { int c = char_id  [b*T_ + t]; v = *(const float4*)(char_table  + (size_t)c*EMB_ + lane*4); }
  else           { int c = bichar_id[b*T_ + t]; v = *(const float4*)(bichar_table+ (size_t)c*EMB_ + (lane-32)*4); }
  s4v o; o[0]=f2bf(v.x); o[1]=f2bf(v.y); o[2]=f2bf(v.z); o[3]=f2bf(v.w);
  *(s4v*)(X_all + ((size_t)rid*E_ + lane*4)) = o;
}

// ---------- K2: persistent-weight MFMA LSTM + emission partials
// 48 blocks: dir=bid&1, bg=(bid>>1)&1, g=bid>>2. 512 threads = 8 waves.
__global__ __launch_bounds__(512) void k_lstm_p(
    const s8v* __restrict__ Apack,
    const short* __restrict__ X_all,
    const float* __restrict__ b_f, const float* __restrict__ b_b,
    const float* __restrict__ w_em,
    short* __restrict__ h_slot,          // [par][dir][bg][32][384] bf16
    int* __restrict__ cnt,               // [dir][bg][512]
    float* __restrict__ em_acc)          // [64][512][13] fp32 (pre-zeroed)
{
  __shared__ short Xs[32][648];          // B operand: [batch][k] (x:0..256, h:256..640)
  __shared__ float gl[128][33];          // gate preacts [4*32 rows][32 batches]
  __shared__ short hsl[32][34];          // new h [uu][b] bf16
  __shared__ float wems[K_][32];
  __shared__ float bsh[128];

  const int bid = blockIdx.x;
  const int dir = bid & 1, bg = (bid>>1)&1, g = bid>>2;
  const int tid = threadIdx.x, lane = tid & 63, w = tid >> 6;

  // persistent A fragments (80 VGPRs)
  s8v frag_a[20];
  {
    const s8v* ap = Apack + ((size_t)((dir*NG_+g)*8 + w)*20)*64 + lane;
    #pragma unroll
    for (int kt = 0; kt < 20; kt++) frag_a[kt] = ap[kt*64];
  }
  if (tid < K_*32) wems[tid>>5][tid&31] = w_em[(size_t)(tid>>5)*(2*H_) + dir*H_ + g*32 + (tid&31)];
  if (tid < 128) {
    const float* bias = dir ? b_b : b_f;
    bsh[tid] = bias[(tid>>5)*H_ + g*32 + (tid&31)];
  }
  // zero h-region of Xs (used at s==0)
  for (int c = tid; c < 32*48; c += 512) {
    int b = c/48, ko = (c%48)*8;
    s8v z = {};
    *(s8v*)&Xs[b][256+ko] = z;
  }
  float cst0 = 0.f, cst1 = 0.f;                 // cell state: (uu=tid&31, b=tid>>5) and b+16
  const int uu_n = tid & 31, b_n = tid >> 5;    // nonlinearity ownership
  __syncthreads();

  const int brow = lane & 15, kch = (lane>>4)*8;

  for (int s = 0; s < T_; s++) {
    const int t  = dir ? (T_-1-s) : s;
    const int tp = dir ? t+1 : t-1;             // previous step index
    // ---- A: load x-part -> Xs[b][0..256)
    #pragma unroll
    for (int i = 0; i < 2; i++) {
      int c = tid + i*512;                       // 0..1023
      int b = c>>5, ko = (c&31)*8;
      *(s8v*)&Xs[b][ko] = *(const s8v*)(X_all + ((size_t)(t*B_ + bg*32 + b)*E_ + ko));
    }
    __syncthreads();

    // ---- x-part MFMA (kt 0..7)
    f4v acc0 = {0.f,0.f,0.f,0.f}, acc1 = {0.f,0.f,0.f,0.f};
    #pragma unroll
    for (int kt = 0; kt < 8; kt++) {
      s8v bq0 = *(const s8v*)&Xs[brow   ][kt*32 + kch];
      s8v bq1 = *(const s8v*)&Xs[16+brow][kt*32 + kch];
      acc0 = __builtin_amdgcn_mfma_f32_16x16x32_bf16(frag_a[kt], bq0, acc0, 0,0,0);
      acc1 = __builtin_amdgcn_mfma_f32_16x16x32_bf16(frag_a[kt], bq1, acc1, 0,0,0);
    }

    if (s > 0) {
      // ---- wait for peers' h[tp]
      if (tid == 0) {
        const int ci = (dir*NBG_ + bg)*T_ + tp;
        while (__hip_atomic_load(&cnt[ci], __ATOMIC_RELAXED, __HIP_MEMORY_SCOPE_AGENT) < GRP_)
          __builtin_amdgcn_s_sleep(1);
      }
      __syncthreads();
      __builtin_amdgcn_fence(__ATOMIC_ACQUIRE, "agent");
      // ---- load h -> Xs[b][256..640)
      const short* hp = h_slot + (size_t)((((tp&1)*2 + dir)*NBG_ + bg))*32*H_;
      #pragma unroll
      for (int i = 0; i < 3; i++) {
        int c = tid + i*512;                     // 0..1535
        int b = c/48, ko = (c%48)*8;
        *(s8v*)&Xs[b][256+ko] = *(const s8v*)(hp + (size_t)b*H_ + ko);
      }
    }
    __syncthreads();

    // ---- h-part MFMA (kt 8..19)
    #pragma unroll
    for (int kt = 8; kt < 20; kt++) {
      s8v bq0 = *(const s8v*)&Xs[brow   ][kt*32 + kch];
      s8v bq1 = *(const s8v*)&Xs[16+brow][kt*32 + kch];
      acc0 = __builtin_amdgcn_mfma_f32_16x16x32_bf16(frag_a[kt], bq0, acc0, 0,0,0);
      acc1 = __builtin_amdgcn_mfma_f32_16x16x32_bf16(frag_a[kt], bq1, acc1, 0,0,0);
    }
    // ---- scatter accumulators to gl: D row=(lane>>4)*4+r (within tile), col=lane&15
    {
      int r0 = w*16 + (lane>>4)*4;
      #pragma unroll
      for (int r = 0; r < 4; r++) {
        gl[r0+r][brow]    = acc0[r];
        gl[r0+r][16+brow] = acc1[r];
      }
    }
    __syncthreads();

    // ---- nonlinearity (2 (uu,b) pairs per thread) + h writes
    {
      float gi = gl[      uu_n][b_n] + bsh[      uu_n];
      float gf = gl[ 32 + uu_n][b_n] + bsh[ 32 + uu_n];
      float gg = gl[ 64 + uu_n][b_n] + bsh[ 64 + uu_n];
      float go = gl[ 96 + uu_n][b_n] + bsh[ 96 + uu_n];
      cst0 = sigm(gf)*cst0 + sigm(gi)*tanh_f(gg);
      float h0 = sigm(go)*tanh_f(cst0);
      int b2 = b_n + 16;
      float gi2 = gl[      uu_n][b2] + bsh[      uu_n];
      float gf2 = gl[ 32 + uu_n][b2] + bsh[ 32 + uu_n];
      float gg2 = gl[ 64 + uu_n][b2] + bsh[ 64 + uu_n];
      float go2 = gl[ 96 + uu_n][b2] + bsh[ 96 + uu_n];
      cst1 = sigm(gf2)*cst1 + sigm(gi2)*tanh_f(gg2);
      float h1 = sigm(go2)*tanh_f(cst1);
      short hb0 = f2bf(h0), hb1 = f2bf(h1);
      hsl[uu_n][b_n] = hb0; hsl[uu_n][b2] = hb1;
      short* hn = h_slot + (size_t)((((t&1)*2 + dir)*NBG_ + bg))*32*H_;
      hn[(size_t)b_n*H_ + g*32 + uu_n] = hb0;
      hn[(size_t)b2 *H_ + g*32 + uu_n] = hb1;
    }
    __syncthreads();                             // drains vmcnt: h stores in L2

    // ---- publish h[t]
    if (tid == 0) {
      __builtin_amdgcn_fence(__ATOMIC_RELEASE, "agent");
      const int ci = (dir*NBG_ + bg)*T_ + t;
      __hip_atomic_fetch_add(&cnt[ci], 1, __ATOMIC_RELAXED, __HIP_MEMORY_SCOPE_AGENT);
    }

    // ---- emission partials: 13 logits x 32 batches
    if (tid < K_*32) {
      int k = tid>>5, b = tid&31;
      float acc = 0.f;
      #pragma unroll
      for (int uu = 0; uu < 32; uu++) acc += bf2f(hsl[uu][b]) * wems[k][uu];
      atomicAdd(&em_acc[((size_t)(bg*32+b)*T_ + t)*K_ + k], acc);
    }
  }
}

// ---------- K3: bias + log_softmax in place on em_acc
__global__ __launch_bounds__(256) void k_em2(float* __restrict__ em, const float* __restrict__ b_em){
  int r = blockIdx.x*256 + threadIdx.x;          // 0..32767
  float e[K_]; float mx = -1e30f;
  #pragma unroll
  for (int k = 0; k < K_; k++) { e[k] = em[(size_t)r*K_+k] + b_em[k]; mx = fmaxf(mx, e[k]); }
  float S = 0.f;
  #pragma unroll
  for (int k = 0; k < K_; k++) S += __expf(e[k]-mx);
  float L = __logf(S) + mx;
  #pragma unroll
  for (int k = 0; k < K_; k++) em[(size_t)r*K_+k] = e[k] - L;
}

// ---------- K4: CRF gold score + forward algorithm (unchanged from r3)
__global__ __launch_bounds__(64) void k_crf(
    const int* __restrict__ char_id, const int* __restrict__ label_id,
    const float* __restrict__ em,
    const float* __restrict__ start_trans, const float* __restrict__ end_trans,
    const float* __restrict__ trans, float* __restrict__ llh)
{
  int b = blockIdx.x, lane = threadIdx.x;
  const int*   cid = char_id  + b*T_;
  const int*   tag = label_id + b*T_;
  const float* emb = em + (size_t)b*T_*K_;

  float sc = 0.f; int cntm = 0;
  for (int t = lane; t < T_; t += 64) {
    int m = (cid[t] != 0);
    cntm += m;
    if (t >= 1 && m) sc += trans[tag[t-1]*K_ + tag[t]] + emb[t*K_ + tag[t]];
  }
  #pragma unroll
  for (int off = 32; off; off >>= 1) { sc += __shfl_xor(sc, off, 64); cntm += __shfl_xor(cntm, off, 64); }

  __shared__ float alpha[K_];
  __shared__ float scoreSh;
  if (lane == 0) {
    int t0 = tag[0];
    int ce = (cntm > 0) ? (cntm - 1) : 0;
    scoreSh = start_trans[t0] + emb[t0] + sc + end_trans[tag[ce]];
  }
  if (lane < K_) alpha[lane] = start_trans[lane] + emb[lane];
  float tr[K_];
  if (lane < K_) {
    #pragma unroll
    for (int i = 0; i < K_; i++) tr[i] = trans[i*K_ + lane];
  }
  __syncthreads();

  for (int t = 1; t < T_; t++) {
    bool mt = (cid[t] != 0);
    float nxt = 0.f;
    if (lane < K_) {
      float a[K_];
      #pragma unroll
      for (int i = 0; i < K_; i++) a[i] = alpha[i] + tr[i];
      float m = a[0];
      #pragma unroll
      for (int i = 1; i < K_; i++) m = fmaxf(m, a[i]);
      float s2 = 0.f;
      #pragma unroll
      for (int i = 0; i < K_; i++) s2 += __expf(a[i]-m);
      nxt = m + __logf(s2) + emb[t*K_ + lane];
    }
    __syncthreads();
    if (lane < K_ && mt) alpha[lane] = nxt;
    __syncthreads();
  }

  if (lane == 0) {
    float m = alpha[0] + end_trans[0];
    #pragma unroll
    for (int k = 1; k < K_; k++) m = fmaxf(m, alpha[k]+end_trans[k]);
    float s2 = 0.f;
    #pragma unroll
    for (int k = 0; k < K_; k++) s2 += __expf(alpha[k]+end_trans[k]-m);
    llh[b] = scoreSh - (m + __logf(s2));
  }
}

// ---------- K5: out = -mean(llh)
__global__ __launch_bounds__(64) void k_final(const float* __restrict__ llh, float* __restrict__ out){
  float v = llh[threadIdx.x];
  #pragma unroll
  for (int off = 32; off; off >>= 1) v += __shfl_xor(v, off, 64);
  if (threadIdx.x == 0) out[0] = -v / (float)B_;
}

extern "C" void kernel_launch(void* const* d_in, const int* in_sizes, int n_in,
                              void* d_out, int out_size, void* d_ws, size_t ws_size,
                              hipStream_t stream)
{
  const int*   char_id      = (const int*)  d_in[0];
  const int*   bichar_id    = (const int*)  d_in[1];
  const int*   label_id     = (const int*)  d_in[2];
  const float* char_table   = (const float*)d_in[3];
  const float* bichar_table = (const float*)d_in[4];
  const float* w_ih_f       = (const float*)d_in[5];
  const float* w_hh_f       = (const float*)d_in[6];
  const float* b_f          = (const float*)d_in[7];
  const float* w_ih_b       = (const float*)d_in[8];
  const float* w_hh_b       = (const float*)d_in[9];
  const float* b_b          = (const float*)d_in[10];
  const float* w_em         = (const float*)d_in[11];
  const float* b_em         = (const float*)d_in[12];
  const float* start_trans  = (const float*)d_in[13];
  const float* end_trans    = (const float*)d_in[14];
  const float* trans        = (const float*)d_in[15];

  char* w = (char*)d_ws;
  s8v*   Apack  = (s8v*)w;   w += (size_t)2*NG_*8*20*64*16;        // 3,932,160
  short* X_all  = (short*)w; w += (size_t)T_*B_*E_*2;              // 16,777,216
  short* h_slot = (short*)w; w += (size_t)2*2*NBG_*32*H_*2;        // 196,608
  float* em_acc = (float*)w; w += (size_t)B_*T_*K_*4;              // 1,703,936
  int*   cnt    = (int*)w;   w += (size_t)2*NBG_*T_*4;             // 8,192
  float* llh    = (float*)w; w += 256;
  // total ~22.6 MB

  hipMemsetAsync(em_acc, 0, (size_t)B_*T_*K_*4 + (size_t)2*NBG_*T_*4, stream);

  k_packA<<<960, 256, 0, stream>>>(w_ih_f, w_hh_f, w_ih_b, w_hh_b, Apack);
  k_embX <<<8192, 256, 0, stream>>>(char_id, bichar_id, char_table, bichar_table, X_all);
  k_lstm_p<<<48, 512, 0, stream>>>(Apack, X_all, b_f, b_b, w_em, h_slot, cnt, em_acc);
  k_em2  <<<128, 256, 0, stream>>>(em_acc, b_em);
  k_crf  <<<64, 64, 0, stream>>>(char_id, label_id, em_acc, start_trans, end_trans, trans, llh);
  k_final<<<1, 64, 0, stream>>>(llh, (float*)d_out);
}

// Round 5
// 3287.816 us; speedup vs baseline: 2.9016x; 1.2035x over previous
//
#include <hip/hip_runtime.h>
#include <math.h>

#define B_    64
#define T_    512
#define EMB_  128
#define E_    256
#define H_    384
#define G4_   1536
#define K_    13
#define NG_   12      // unit-groups per dir (32 units each)
#define NBG_  2       // batch-groups (32 batches each)

typedef short s8v  __attribute__((ext_vector_type(8)));
typedef short s4v  __attribute__((ext_vector_type(4)));
typedef float f4v  __attribute__((ext_vector_type(4)));

__device__ __forceinline__ float sigm(float x){ return 1.f/(1.f+__expf(-x)); }
__device__ __forceinline__ float tanh_f(float x){ return 2.f/(1.f+__expf(-2.f*x)) - 1.f; }
__device__ __forceinline__ short f2bf(float x){
  unsigned u = __builtin_bit_cast(unsigned, x);
  return (short)((u + 0x7FFFu + ((u>>16)&1u)) >> 16);
}
__device__ __forceinline__ float bf2f(short s){
  return __builtin_bit_cast(float, ((unsigned)(unsigned short)s) << 16);
}
__device__ __forceinline__ size_t slotbase(int par, int dir, int bg){
  return (size_t)(((par*2 + dir)*NBG_ + bg)) * (32*H_);
}

// ---------- K0: pack weights into per-lane MFMA A-fragments (bf16)
__global__ __launch_bounds__(256) void k_packA(
    const float* __restrict__ wih_f, const float* __restrict__ whh_f,
    const float* __restrict__ wih_b, const float* __restrict__ whh_b,
    s8v* __restrict__ Apack)
{
  int idx = blockIdx.x*256 + threadIdx.x;            // 0..245759
  if (idx >= 2*NG_*8*20*64) return;
  int l   = idx & 63;
  int kt  = (idx>>6) % 20;
  int w   = ((idx>>6)/20) % 8;
  int g   = ((idx>>6)/160) % NG_;
  int dir = (idx>>6)/(160*NG_);
  const float* wih = dir ? wih_b : wih_f;
  const float* whh = dir ? whh_b : whh_f;
  int R = (w>>1)*384 + g*32 + (w&1)*16 + (l&15);
  int kbase = kt*32 + (l>>4)*8;
  const float* src = (kbase < E_) ? (wih + (size_t)R*E_ + kbase)
                                  : (whh + (size_t)R*H_ + (kbase - E_));
  s8v out;
  #pragma unroll
  for (int e = 0; e < 8; e++) out[e] = f2bf(src[e]);
  Apack[idx] = out;
}

// ---------- K1: gather embeddings -> X_all[t][b][256] bf16
__global__ __launch_bounds__(256) void k_embX(
    const int* __restrict__ char_id, const int* __restrict__ bichar_id,
    const float* __restrict__ char_table, const float* __restrict__ bichar_table,
    short* __restrict__ X_all)
{
  int rid  = blockIdx.x*4 + (threadIdx.x>>6);        // 0..32767 = t*64+b
  int lane = threadIdx.x & 63;
  int t = rid >> 6, b = rid & 63;
  float4 v;
  if (lane < 32) { int c = char_id  [b*T_ + t]; v = *(const float4*)(char_table  + (size_t)c*EMB_ + lane*4); }
  else           { int c = bichar_id[b*T_ + t]; v = *(const float4*)(bichar_table+ (size_t)c*EMB_ + (lane-32)*4); }
  s4v o; o[0]=f2bf(v.x); o[1]=f2bf(v.y); o[2]=f2bf(v.z); o[3]=f2bf(v.w);
  *(s4v*)(X_all + ((size_t)rid*E_ + lane*4)) = o;
}

// ---------- K2: persistent-weight MFMA LSTM, lock-free tagged h exchange
// 48 blocks: dir=bid&1, bg=(bid>>1)&1, g=bid>>2. 512 threads = 8 waves.
__global__ __launch_bounds__(512) void k_lstm_p(
    const s8v* __restrict__ Apack,
    const short* __restrict__ X_all,
    const float* __restrict__ b_f, const float* __restrict__ b_b,
    const float* __restrict__ w_em,
    unsigned* __restrict__ h_slot,       // [2][dir][bg][32 b][384 u] u32 = (bf16<<16)|t
    float* __restrict__ em_acc)          // [64][512][13] fp32 (pre-zeroed)
{
  __shared__ short Xs[32][648];          // B operand: [batch][k] (x:0..256, h:256..640)
  __shared__ float gl[128][33];          // gate preacts [4*32 rows][32 batches]
  __shared__ short hsl[32][34];          // new h [uu][b] bf16 (for emission)
  __shared__ float wems[K_][32];
  __shared__ float bsh[128];

  const int bid = blockIdx.x;
  const int dir = bid & 1, bg = (bid>>1)&1, g = bid>>2;
  const int tid = threadIdx.x, lane = tid & 63, w = tid >> 6;

  // persistent A fragments (80 regs, unified VGPR/AGPR file)
  s8v frag_a[20];
  {
    const s8v* ap = Apack + ((size_t)((dir*NG_+g)*8 + w)*20)*64 + lane;
    #pragma unroll
    for (int kt = 0; kt < 20; kt++) frag_a[kt] = ap[kt*64];
  }
  if (tid < K_*32) wems[tid>>5][tid&31] = w_em[(size_t)(tid>>5)*(2*H_) + dir*H_ + g*32 + (tid&31)];
  if (tid < 128) {
    const float* bias = dir ? b_b : b_f;
    bsh[tid] = bias[(tid>>5)*H_ + g*32 + (tid&31)];
  }
  for (int c = tid; c < 32*48; c += 512) {        // zero h-region (used at s==0)
    int b = c/48, ko = (c%48)*8;
    s8v z = {};
    *(s8v*)&Xs[b][256+ko] = z;
  }
  float cst0 = 0.f, cst1 = 0.f;
  const int uu_n = tid & 31, b_n = tid >> 5;      // nonlinearity ownership (b_n, b_n+16)
  const int b_r = tid >> 4, ch = tid & 15;        // reader ownership: 32 b x 16 chunks(24u)
  __syncthreads();

  const int brow = lane & 15, kch = (lane>>4)*8;

  for (int s = 0; s < T_; s++) {
    const int t  = dir ? (T_-1-s) : s;
    const int tp = dir ? t+1 : t-1;

    // ---- A1: x-part -> Xs[b][0..256)  (issue early; L2-cached)
    #pragma unroll
    for (int i = 0; i < 2; i++) {
      int c = tid + i*512;
      int b = c>>5, ko = (c&31)*8;
      *(s8v*)&Xs[b][ko] = *(const s8v*)(X_all + ((size_t)(t*B_ + bg*32 + b)*E_ + ko));
    }

    // ---- A2: poll peers' tagged h[tp] words, unpack into Xs[b][256..640)
    if (s > 0) {
      const unsigned tag = (unsigned)(tp & 0xFFFF);
      const unsigned long long tagpair = (unsigned long long)tag | ((unsigned long long)tag << 32);
      const unsigned long long* hp =
          (const unsigned long long*)(h_slot + slotbase(tp&1, dir, bg)) + ((size_t)b_r*H_ + ch*24)/2;
      unsigned long long vals[12];
      unsigned done = 0;
      while (done != 0xFFFu) {
        #pragma unroll
        for (int i = 0; i < 12; i++) {
          if (!((done >> i) & 1u)) {
            unsigned long long v = __hip_atomic_load(hp + i, __ATOMIC_RELAXED, __HIP_MEMORY_SCOPE_AGENT);
            if (((v ^ tagpair) & 0x0000FFFF0000FFFFull) == 0ull) { vals[i] = v; done |= (1u << i); }
          }
        }
      }
      #pragma unroll
      for (int i = 0; i < 12; i++) {
        unsigned lo = (unsigned)vals[i], hi = (unsigned)(vals[i] >> 32);
        unsigned packed = (lo >> 16) | (hi & 0xFFFF0000u);
        *(unsigned*)&Xs[b_r][256 + ch*24 + 2*i] = packed;
      }
    }
    __syncthreads();                                  // S1

    // ---- B: 20 MFMA (x + h), then scatter to gl
    f4v acc0 = {0.f,0.f,0.f,0.f}, acc1 = {0.f,0.f,0.f,0.f};
    #pragma unroll
    for (int kt = 0; kt < 20; kt++) {
      s8v bq0 = *(const s8v*)&Xs[brow   ][kt*32 + kch];
      s8v bq1 = *(const s8v*)&Xs[16+brow][kt*32 + kch];
      acc0 = __builtin_amdgcn_mfma_f32_16x16x32_bf16(frag_a[kt], bq0, acc0, 0,0,0);
      acc1 = __builtin_amdgcn_mfma_f32_16x16x32_bf16(frag_a[kt], bq1, acc1, 0,0,0);
    }
    {
      int r0 = w*16 + (lane>>4)*4;
      #pragma unroll
      for (int r = 0; r < 4; r++) {
        gl[r0+r][brow]    = acc0[r];
        gl[r0+r][16+brow] = acc1[r];
      }
    }
    __syncthreads();                                  // S2

    // ---- C: nonlinearity; publish h IMMEDIATELY (tagged, relaxed agent stores)
    {
      float gi = gl[      uu_n][b_n] + bsh[      uu_n];
      float gf = gl[ 32 + uu_n][b_n] + bsh[ 32 + uu_n];
      float gg = gl[ 64 + uu_n][b_n] + bsh[ 64 + uu_n];
      float go = gl[ 96 + uu_n][b_n] + bsh[ 96 + uu_n];
      cst0 = sigm(gf)*cst0 + sigm(gi)*tanh_f(gg);
      float h0 = sigm(go)*tanh_f(cst0);
      int b2 = b_n + 16;
      float gi2 = gl[      uu_n][b2] + bsh[      uu_n];
      float gf2 = gl[ 32 + uu_n][b2] + bsh[ 32 + uu_n];
      float gg2 = gl[ 64 + uu_n][b2] + bsh[ 64 + uu_n];
      float go2 = gl[ 96 + uu_n][b2] + bsh[ 96 + uu_n];
      cst1 = sigm(gf2)*cst1 + sigm(gi2)*tanh_f(gg2);
      float h1 = sigm(go2)*tanh_f(cst1);
      short hb0 = f2bf(h0), hb1 = f2bf(h1);
      unsigned vtag = (unsigned)(t & 0xFFFF);
      unsigned v0 = ((unsigned)(unsigned short)hb0 << 16) | vtag;
      unsigned v1 = ((unsigned)(unsigned short)hb1 << 16) | vtag;
      unsigned* hw = h_slot + slotbase(t&1, dir, bg);
      unsigned uglob = g*32 + uu_n;
      __hip_atomic_store(hw + (size_t)b_n*H_ + uglob, v0, __ATOMIC_RELAXED, __HIP_MEMORY_SCOPE_AGENT);
      __hip_atomic_store(hw + (size_t)b2 *H_ + uglob, v1, __ATOMIC_RELAXED, __HIP_MEMORY_SCOPE_AGENT);
      hsl[uu_n][b_n] = hb0; hsl[uu_n][b2] = hb1;
    }
    __syncthreads();                                  // S3

    // ---- D: emission partials (off critical path)
    if (tid < K_*32) {
      int k = tid>>5, b = tid&31;
      float acc = 0.f;
      #pragma unroll
      for (int uu = 0; uu < 32; uu++) acc += bf2f(hsl[uu][b]) * wems[k][uu];
      atomicAdd(&em_acc[((size_t)(bg*32+b)*T_ + t)*K_ + k], acc);
    }
  }
}

// ---------- K3: bias + log_softmax in place on em_acc
__global__ __launch_bounds__(256) void k_em2(float* __restrict__ em, const float* __restrict__ b_em){
  int r = blockIdx.x*256 + threadIdx.x;
  float e[K_]; float mx = -1e30f;
  #pragma unroll
  for (int k = 0; k < K_; k++) { e[k] = em[(size_t)r*K_+k] + b_em[k]; mx = fmaxf(mx, e[k]); }
  float S = 0.f;
  #pragma unroll
  for (int k = 0; k < K_; k++) S += __expf(e[k]-mx);
  float L = __logf(S) + mx;
  #pragma unroll
  for (int k = 0; k < K_; k++) em[(size_t)r*K_+k] = e[k] - L;
}

// ---------- K4: CRF gold score + forward algorithm
__global__ __launch_bounds__(64) void k_crf(
    const int* __restrict__ char_id, const int* __restrict__ label_id,
    const float* __restrict__ em,
    const float* __restrict__ start_trans, const float* __restrict__ end_trans,
    const float* __restrict__ trans, float* __restrict__ llh)
{
  int b = blockIdx.x, lane = threadIdx.x;
  const int*   cid = char_id  + b*T_;
  const int*   tag = label_id + b*T_;
  const float* emb = em + (size_t)b*T_*K_;

  float sc = 0.f; int cntm = 0;
  for (int t = lane; t < T_; t += 64) {
    int m = (cid[t] != 0);
    cntm += m;
    if (t >= 1 && m) sc += trans[tag[t-1]*K_ + tag[t]] + emb[t*K_ + tag[t]];
  }
  #pragma unroll
  for (int off = 32; off; off >>= 1) { sc += __shfl_xor(sc, off, 64); cntm += __shfl_xor(cntm, off, 64); }

  __shared__ float alpha[K_];
  __shared__ float scoreSh;
  if (lane == 0) {
    int t0 = tag[0];
    int ce = (cntm > 0) ? (cntm - 1) : 0;
    scoreSh = start_trans[t0] + emb[t0] + sc + end_trans[tag[ce]];
  }
  if (lane < K_) alpha[lane] = start_trans[lane] + emb[lane];
  float tr[K_];
  if (lane < K_) {
    #pragma unroll
    for (int i = 0; i < K_; i++) tr[i] = trans[i*K_ + lane];
  }
  __syncthreads();

  for (int t = 1; t < T_; t++) {
    bool mt = (cid[t] != 0);
    float nxt = 0.f;
    if (lane < K_) {
      float a[K_];
      #pragma unroll
      for (int i = 0; i < K_; i++) a[i] = alpha[i] + tr[i];
      float m = a[0];
      #pragma unroll
      for (int i = 1; i < K_; i++) m = fmaxf(m, a[i]);
      float s2 = 0.f;
      #pragma unroll
      for (int i = 0; i < K_; i++) s2 += __expf(a[i]-m);
      nxt = m + __logf(s2) + emb[t*K_ + lane];
    }
    __syncthreads();
    if (lane < K_ && mt) alpha[lane] = nxt;
    __syncthreads();
  }

  if (lane == 0) {
    float m = alpha[0] + end_trans[0];
    #pragma unroll
    for (int k = 1; k < K_; k++) m = fmaxf(m, alpha[k]+end_trans[k]);
    float s2 = 0.f;
    #pragma unroll
    for (int k = 0; k < K_; k++) s2 += __expf(alpha[k]+end_trans[k]-m);
    llh[b] = scoreSh - (m + __logf(s2));
  }
}

// ---------- K5: out = -mean(llh)
__global__ __launch_bounds__(64) void k_final(const float* __restrict__ llh, float* __restrict__ out){
  float v = llh[threadIdx.x];
  #pragma unroll
  for (int off = 32; off; off >>= 1) v += __shfl_xor(v, off, 64);
  if (threadIdx.x == 0) out[0] = -v / (float)B_;
}

extern "C" void kernel_launch(void* const* d_in, const int* in_sizes, int n_in,
                              void* d_out, int out_size, void* d_ws, size_t ws_size,
                              hipStream_t stream)
{
  const int*   char_id      = (const int*)  d_in[0];
  const int*   bichar_id    = (const int*)  d_in[1];
  const int*   label_id     = (const int*)  d_in[2];
  const float* char_table   = (const float*)d_in[3];
  const float* bichar_table = (const float*)d_in[4];
  const float* w_ih_f       = (const float*)d_in[5];
  const float* w_hh_f       = (const float*)d_in[6];
  const float* b_f          = (const float*)d_in[7];
  const float* w_ih_b       = (const float*)d_in[8];
  const float* w_hh_b       = (const float*)d_in[9];
  const float* b_b          = (const float*)d_in[10];
  const float* w_em         = (const float*)d_in[11];
  const float* b_em         = (const float*)d_in[12];
  const float* start_trans  = (const float*)d_in[13];
  const float* end_trans    = (const float*)d_in[14];
  const float* trans        = (const float*)d_in[15];

  char* w = (char*)d_ws;
  s8v*      Apack  = (s8v*)w;      w += (size_t)2*NG_*8*20*64*16;     // 3,932,160
  short*    X_all  = (short*)w;    w += (size_t)T_*B_*E_*2;           // 16,777,216
  unsigned* h_slot = (unsigned*)w; w += (size_t)2*2*NBG_*32*H_*4;     // 393,216
  float*    em_acc = (float*)w;    w += (size_t)B_*T_*K_*4;           // 1,703,936
  float*    llh    = (float*)w;    w += 256;
  // total ~22.8 MB

  hipMemsetAsync(em_acc, 0, (size_t)B_*T_*K_*4, stream);

  k_packA<<<960, 256, 0, stream>>>(w_ih_f, w_hh_f, w_ih_b, w_hh_b, Apack);
  k_embX <<<8192, 256, 0, stream>>>(char_id, bichar_id, char_table, bichar_table, X_all);
  k_lstm_p<<<48, 512, 0, stream>>>(Apack, X_all, b_f, b_b, w_em, h_slot, em_acc);
  k_em2  <<<128, 256, 0, stream>>>(em_acc, b_em);
  k_crf  <<<64, 64, 0, stream>>>(char_id, label_id, em_acc, start_trans, end_trans, trans, llh);
  k_final<<<1, 64, 0, stream>>>(llh, (float*)d_out);
}